// Round 2
// baseline (1535.201 us; speedup 1.0000x reference)
//
#include <hip/hip_runtime.h>
#include <hip/hip_bf16.h>

// DigitCaps routing, fused. Key identity: the routing logits are linear in v:
//   b_k[b,r,c] = u_hat[b,r,c,:] . (v_1+...+v_{k-1})[b,c,:]  (= uh . Vsum)
// so no [B,R,C] logit state is materialized; u_hat is recomputed per pass
// entirely in registers. 3x (pass + squash) kernels, ~60 MB total HBM traffic.
//
// Round-1 fix: d_out is FLOAT32 (reference returns f32; bf16 writes into the
// f32 buffer produced the 1.39 misalignment error). Also: safe atomicAdd for
// the global flush (CAS works on any memory type; flush traffic is tiny).

#define NBATCH 512
#define NR     1152
#define NCLS   10
#define NOUT   16
#define RCHUNK 18          // r-rows per block; grid.x = 1152/18 = 64
#define CO     160         // NCLS*NOUT

__device__ __forceinline__ unsigned short f2bf_rne(float x) {
    unsigned u = __float_as_uint(x);
    return (unsigned short)((u + 0x7fffu + ((u >> 16) & 1u)) >> 16);
}

template<bool FIRST>
__global__ __launch_bounds__(256, 2)
void caps_pass(const float* __restrict__ U, const float* __restrict__ W,
               const float* __restrict__ Vsum, float* __restrict__ Sg)
{
    // stride 161 floats (odd) -> lane b and b+32 share a bank: 2-way = free
    __shared__ float s_part[64][161];            // 41.2 KB partial s, lane-owned rows
    __shared__ unsigned short vs_l[64][162];     // 20.7 KB bf16 Vsum (stride 81 dwords, odd)

    const int tid  = threadIdx.x;
    const int lane = tid & 63;
    const int b0   = ((int)blockIdx.y) << 6;     // 64 batches per block, lane = batch

    for (int idx = tid; idx < 64 * 161; idx += 256)
        (&s_part[0][0])[idx] = 0.0f;
    if (!FIRST) {
        for (int idx = tid; idx < 64 * CO; idx += 256) {
            int bl = idx / CO;
            int m  = idx - bl * CO;
            vs_l[bl][m] = f2bf_rne(Vsum[(size_t)(b0 + bl) * CO + m]);
        }
    }
    __syncthreads();

    // wave id forced to SGPR so r (and all W addresses) are provably uniform
    const int wv    = __builtin_amdgcn_readfirstlane(tid >> 6);
    const int rbase = (int)blockIdx.x * RCHUNK;
    const size_t ubase = (size_t)(b0 + lane) * (NR * 8);

    for (int r = rbase + wv; r < rbase + RCHUNK; r += 4) {
        const float4* up = reinterpret_cast<const float4*>(U + ubase + (size_t)r * 8);
        float4 u0 = up[0], u1 = up[1];
        const float uu[8] = {u0.x,u0.y,u0.z,u0.w, u1.x,u1.y,u1.z,u1.w};

        const float* wr = W + (size_t)r * (NCLS * 128);   // W[r][c][i][o]

        float uh[NCLS][NOUT];                    // 160 VGPRs, all indexing static
        #pragma unroll
        for (int c = 0; c < NCLS; ++c) {
            #pragma unroll
            for (int o = 0; o < NOUT; ++o) uh[c][o] = 0.0f;
            #pragma unroll
            for (int i = 0; i < 8; ++i) {
                const float4* wp = reinterpret_cast<const float4*>(wr + c * 128 + i * 16);
                float4 w0 = wp[0], w1 = wp[1], w2 = wp[2], w3 = wp[3];
                const float wf[16] = {w0.x,w0.y,w0.z,w0.w, w1.x,w1.y,w1.z,w1.w,
                                      w2.x,w2.y,w2.z,w2.w, w3.x,w3.y,w3.z,w3.w};
                const float ui = uu[i];
                #pragma unroll
                for (int o = 0; o < NOUT; ++o)
                    uh[c][o] = __builtin_fmaf(ui, wf[o], uh[c][o]);
            }
        }

        float coef[NCLS];
        if (FIRST) {
            // Vsum == 0 -> logits 0 -> softmax uniform
            #pragma unroll
            for (int c = 0; c < NCLS; ++c) coef[c] = 0.1f;
        } else {
            float lg[NCLS];
            #pragma unroll
            for (int c = 0; c < NCLS; ++c) {
                float acc = 0.0f;
                #pragma unroll
                for (int o2 = 0; o2 < 8; ++o2) {
                    const unsigned pv =
                        *reinterpret_cast<const unsigned*>(&vs_l[lane][c * 16 + o2 * 2]);
                    acc = __builtin_fmaf(uh[c][o2*2],     __uint_as_float(pv << 16), acc);
                    acc = __builtin_fmaf(uh[c][o2*2 + 1], __uint_as_float(pv & 0xffff0000u), acc);
                }
                lg[c] = acc;
            }
            float mx = lg[0];
            #pragma unroll
            for (int c = 1; c < NCLS; ++c) mx = fmaxf(mx, lg[c]);
            float den = 0.0f;
            #pragma unroll
            for (int c = 0; c < NCLS; ++c) { float e = __expf(lg[c] - mx); coef[c] = e; den += e; }
            const float inv = 1.0f / den;
            #pragma unroll
            for (int c = 0; c < NCLS; ++c) coef[c] *= inv;
        }

        // lane-exclusive rows within a wave; atomic only vs the other 3 waves
        #pragma unroll
        for (int c = 0; c < NCLS; ++c) {
            const float cc = coef[c];
            #pragma unroll
            for (int o = 0; o < NOUT; ++o)
                atomicAdd(&s_part[lane][c * 16 + o], cc * uh[c][o]);
        }
    }

    __syncthreads();

    for (int idx = tid; idx < 64 * CO; idx += 256) {
        int bl = idx / CO;
        int m  = idx - bl * CO;
        atomicAdd(&Sg[(size_t)(b0 + bl) * CO + m], s_part[bl][m]);
    }
}

__global__ __launch_bounds__(256)
void caps_squash(float* __restrict__ S, float* __restrict__ Vsum,
                 float* __restrict__ out, const int final_pass)
{
    const int idx = (int)blockIdx.x * 256 + threadIdx.x;   // flat (b*NCLS + c)
    if (idx >= NBATCH * NCLS) return;
    float* sp = S + (size_t)idx * NOUT;
    const float4* s4 = reinterpret_cast<const float4*>(sp);
    float4 a = s4[0], b = s4[1], c = s4[2], d = s4[3];
    const float sv[16] = {a.x,a.y,a.z,a.w, b.x,b.y,b.z,b.w,
                          c.x,c.y,c.z,c.w, d.x,d.y,d.z,d.w};
    float ss = 0.0f;
    #pragma unroll
    for (int o = 0; o < NOUT; ++o) ss = __builtin_fmaf(sv[o], sv[o], ss);
    // ss/(norm*(1+ss)) == norm/(1+ss)
    const float f = sqrtf(ss) / (1.0f + ss);
    if (final_pass) {
        #pragma unroll
        for (int o = 0; o < NOUT; ++o)
            out[(size_t)idx * NOUT + o] = f * sv[o];       // f32 output
    } else {
        float* vp = Vsum + (size_t)idx * NOUT;
        #pragma unroll
        for (int o = 0; o < NOUT; ++o) vp[o] += f * sv[o];
        #pragma unroll
        for (int o = 0; o < NOUT; ++o) sp[o] = 0.0f;   // s zeroed for next pass
    }
}

extern "C" void kernel_launch(void* const* d_in, const int* in_sizes, int n_in,
                              void* d_out, int out_size, void* d_ws, size_t ws_size,
                              hipStream_t stream)
{
    (void)in_sizes; (void)n_in; (void)out_size; (void)ws_size;
    const float* U = (const float*)d_in[0];         // [512][1152][8] f32
    const float* W = (const float*)d_in[1];         // [1][1152][10][8][16] f32
    float* S    = (float*)d_ws;                     // [512][10][16] f32 accumulators
    float* Vsum = S + (size_t)NBATCH * CO;          // [512][10][16] f32 running v-sum
    float* out  = (float*)d_out;                    // [512][10][16] f32

    hipMemsetAsync(d_ws, 0, (size_t)2 * NBATCH * CO * sizeof(float), stream);

    dim3 grid(NR / RCHUNK, NBATCH / 64);            // (64, 8) = 512 blocks
    dim3 blk(256);
    dim3 sgrid((NBATCH * NCLS + 255) / 256);        // 20 blocks

    caps_pass<true ><<<grid, blk, 0, stream>>>(U, W, Vsum, S);
    caps_squash<<<sgrid, blk, 0, stream>>>(S, Vsum, nullptr, 0);
    caps_pass<false><<<grid, blk, 0, stream>>>(U, W, Vsum, S);
    caps_squash<<<sgrid, blk, 0, stream>>>(S, Vsum, nullptr, 0);
    caps_pass<false><<<grid, blk, 0, stream>>>(U, W, Vsum, S);
    caps_squash<<<sgrid, blk, 0, stream>>>(S, Vsum, out, 1);
}